// Round 3
// baseline (1078.284 us; speedup 1.0000x reference)
//
#include <hip/hip_runtime.h>

#define N_FEAT  200000
#define DIM     512
#define KPROTO  64
#define CHUNK   32
#define NCHUNKS (N_FEAT / CHUNK)   // 6250 exact

typedef _Float16 f16;
typedef __fp16   h16x2 __attribute__((ext_vector_type(2)));   // cvt_pkrtz return type
typedef _Float16 f16x8 __attribute__((ext_vector_type(8)));
typedef float    f32x4 __attribute__((ext_vector_type(4)));
typedef unsigned int u32;

union H8 { f16x8 v; h16x2 h[4]; };

// ws layout (bytes):
//   [0,      65536)   Ph     f16 [64][512]
//   [65536,  65792)   counts int [64]
//   [66048,  266048)  asg    u8  [200000]
//   [266240, ...)     partials f32 [4*G][64][128]   (G adapted to ws_size)
#define CNT_OFF   65536
#define ASG_OFF   66048
#define PART_OFF  266240
#define SLICE_ELEMS (KPROTO * 128)   // 8192 floats = 32 KB per block

__device__ __forceinline__ void load_lds16(const float* g, float* l) {
    __builtin_amdgcn_global_load_lds(
        (const __attribute__((address_space(1))) u32*)g,
        (__attribute__((address_space(3))) u32*)l, 16, 0, 0);
}

// ---------------------------------------------------------------- proto prep
__global__ __launch_bounds__(256) void proto_prep(const float* __restrict__ P,
                                                  f16* __restrict__ Ph) {
    __shared__ float red[4];
    __shared__ float s_scale;
    int k = blockIdx.x, t = threadIdx.x;
    const float* row = P + k * DIM;
    float a = row[t], b = row[t + 256];
    float ss = a * a + b * b;
    #pragma unroll
    for (int off = 32; off; off >>= 1) ss += __shfl_down(ss, off);
    if ((t & 63) == 0) red[t >> 6] = ss;
    __syncthreads();
    if (t == 0) {
        float tot = red[0] + red[1] + red[2] + red[3];
        s_scale = 1.0f / fmaxf(sqrtf(tot), 1e-8f);
    }
    __syncthreads();
    float sc = s_scale;
    Ph[k * DIM + t]       = (f16)(a * sc);
    Ph[k * DIM + t + 256] = (f16)(b * sc);
}

// ---------------------------------------------------------------- assignment
// 4 waves/block; wave w owns proto tile [w*16, w*16+16) with B-frags resident.
// Staging: async global->LDS, f32, 16B/lane, XOR-swizzled source so LDS row r
// holds its 16B chunks permuted by (chunk_low3 ^ (r&7)).
__global__ __launch_bounds__(256, 2) void assign_k(const float* __restrict__ F,
                                                   const f16* __restrict__ Ph,
                                                   unsigned char* __restrict__ asg,
                                                   int* __restrict__ counts) {
    __shared__ __align__(16) float Al[CHUNK * DIM];   // 64 KB
    __shared__ float sims[CHUNK * 65];                // 8.3 KB
    __shared__ int hist[KPROTO];

    int t = threadIdx.x, lane = t & 63, wid = t >> 6;
    int cq = lane >> 4, cl = lane & 15;
    if (t < KPROTO) hist[t] = 0;

    // B fragments: B[n = wid*16+cl][k = cq*8 + ks*32 + j]
    f16x8 bfrag[16];
    {
        const f16* pb = Ph + (wid * 16 + cl) * DIM + cq * 8;
        #pragma unroll
        for (int ks = 0; ks < 16; ++ks) bfrag[ks] = *(const f16x8*)(pb + ks * 32);
    }
    __syncthreads();

    for (int ch = blockIdx.x; ch < NCHUNKS; ch += gridDim.x) {
        // ---- async stage: wave wid stages rows [wid*8, wid*8+8), 2 KB each
        const float* gbase = F + (size_t)ch * (CHUNK * DIM);
        #pragma unroll
        for (int rr = 0; rr < 8; ++rr) {
            int r = wid * 8 + rr;
            const float* gsrc = gbase + r * DIM + ((lane ^ rr) << 2);
            load_lds16(gsrc,        Al + r * DIM);
            load_lds16(gsrc + 256,  Al + r * DIM + 256);
        }
        __syncthreads();   // drains vmcnt: staged data visible

        // ---- MFMA sims: 2 rowtiles x 16 ksteps, cvt f32->f16 at frag build
        int sw = cl & 7;
        #pragma unroll
        for (int rt = 0; rt < 2; ++rt) {
            f32x4 acc = {0.f, 0.f, 0.f, 0.f};
            const float* arow = Al + (rt * 16 + cl) * DIM;
            #pragma unroll
            for (int ks = 0; ks < 16; ++ks) {
                int p0 = ks * 8 + ((cq * 2) ^ sw);   // physical chunk of logical l0
                int p1 = p0 ^ 1;                      // logical l0^1 lives at p0^1
                f32x4 lo = *(const f32x4*)(arow + p0 * 4);
                f32x4 hi = *(const f32x4*)(arow + p1 * 4);
                H8 a;
                a.h[0] = __builtin_amdgcn_cvt_pkrtz(lo.x, lo.y);
                a.h[1] = __builtin_amdgcn_cvt_pkrtz(lo.z, lo.w);
                a.h[2] = __builtin_amdgcn_cvt_pkrtz(hi.x, hi.y);
                a.h[3] = __builtin_amdgcn_cvt_pkrtz(hi.z, hi.w);
                acc = __builtin_amdgcn_mfma_f32_16x16x32_f16(a.v, bfrag[ks], acc, 0, 0, 0);
            }
            #pragma unroll
            for (int r = 0; r < 4; ++r)
                sims[(rt * 16 + cq * 4 + r) * 65 + wid * 16 + cl] = acc[r];
        }
        __syncthreads();   // sims complete; Al reads complete (safe to restage)

        // ---- argmax per row (wave 0 only), first-max tie-break
        if (t < CHUNK) {
            const float* srow = sims + t * 65;
            float best = srow[0]; int bi = 0;
            #pragma unroll 8
            for (int j = 1; j < KPROTO; ++j) {
                float v = srow[j];
                if (v > best) { best = v; bi = j; }
            }
            asg[ch * CHUNK + t] = (unsigned char)bi;
            atomicAdd(&hist[bi], 1);
        }
        // next stage writes Al (ok), sims rewritten only after next barrier
    }
    __syncthreads();
    if (t < KPROTO) atomicAdd(&counts[t], hist[t]);
}

// ---------------------------------------------------------------- segment sum
// Grid = 4*G blocks; block = (group g, slice s). LDS acc [64][128] = 32 KB.
// Lane-half c owns cols {c, c+32, c+64, c+96} of the slice -> LDS atomics are
// 2-way bank (free). Flush NON-atomically to partials[block].
__global__ __launch_bounds__(256, 2) void segsum_k(const float* __restrict__ F,
                                                   const unsigned char* __restrict__ asg,
                                                   float* __restrict__ partials,
                                                   int nGroups) {
    __shared__ float acc[SLICE_ELEMS];
    int t = threadIdx.x;
    int s = blockIdx.x & 3;
    int g = blockIdx.x >> 2;
    #pragma unroll
    for (int m = 0; m < 32; ++m) acc[t + m * 256] = 0.f;
    __syncthreads();

    int lane = t & 63, wid = t >> 6;
    int c = lane & 31, half = lane >> 5;
    int gw = g * 4 + wid;
    int step = nGroups * 4 * 8;            // pairs advanced per loop
    const float* Fs = F + s * 128;

    const int NPAIR = N_FEAT / 2;          // 100000 = 12500 groups of 8, no tail
    for (int pb = gw * 8; pb < NPAIR; pb += step) {
        int a[8]; float v[8][4];
        #pragma unroll
        for (int u = 0; u < 8; ++u) {
            int p = pb + u;
            unsigned short a2 = *(const unsigned short*)(asg + p * 2);
            a[u] = (a2 >> (half * 8)) & 255;
            const float* src = Fs + (size_t)(p * 2 + half) * DIM + c;
            v[u][0] = src[0]; v[u][1] = src[32]; v[u][2] = src[64]; v[u][3] = src[96];
        }
        #pragma unroll
        for (int u = 0; u < 8; ++u) {
            float* d = acc + a[u] * 128 + c;
            atomicAdd(d,      v[u][0]);
            atomicAdd(d + 32, v[u][1]);
            atomicAdd(d + 64, v[u][2]);
            atomicAdd(d + 96, v[u][3]);
        }
    }
    __syncthreads();

    float4* dst = (float4*)(partials + (size_t)blockIdx.x * SLICE_ELEMS);
    const float4* sa = (const float4*)acc;
    #pragma unroll
    for (int m = 0; m < 8; ++m) dst[t + m * 256] = sa[t + m * 256];
}

// ---------------------------------------------------------------- reduce + EMA
__global__ __launch_bounds__(256) void reduce_ema(const float* __restrict__ partials,
                                                  const int* __restrict__ counts,
                                                  const float* __restrict__ P,
                                                  float* __restrict__ out, int G) {
    int tid = blockIdx.x * 256 + threadIdx.x;   // 0..8191
    int base = tid * 4;
    int k = base >> 9, d = base & 511;
    int s = d >> 7, i = d & 127;
    const float* p0 = partials + (size_t)s * SLICE_ELEMS + k * 128 + i;
    float4 sum = {0.f, 0.f, 0.f, 0.f};
    for (int g = 0; g < G; ++g) {
        float4 v = *(const float4*)(p0 + (size_t)g * 4 * SLICE_ELEMS);
        sum.x += v.x; sum.y += v.y; sum.z += v.z; sum.w += v.w;
    }
    float4 pr = *(const float4*)(P + base);
    float4 o = pr;
    int cnt = counts[k];
    if (cnt > 0) {
        float inv = 1.0f / (float)cnt;
        o.x = 0.9f * pr.x + 0.1f * (sum.x * inv);
        o.y = 0.9f * pr.y + 0.1f * (sum.y * inv);
        o.z = 0.9f * pr.z + 0.1f * (sum.z * inv);
        o.w = 0.9f * pr.w + 0.1f * (sum.w * inv);
    }
    *(float4*)(out + base) = o;
}

// ---------------------------------------------------------------- launch
extern "C" void kernel_launch(void* const* d_in, const int* in_sizes, int n_in,
                              void* d_out, int out_size, void* d_ws, size_t ws_size,
                              hipStream_t stream) {
    const float* F = (const float*)d_in[0];
    const float* P = (const float*)d_in[1];
    char* ws = (char*)d_ws;
    f16*   Ph       = (f16*)ws;
    int*   counts   = (int*)(ws + CNT_OFF);
    unsigned char* asg = (unsigned char*)(ws + ASG_OFF);
    float* partials = (float*)(ws + PART_OFF);
    float* out = (float*)d_out;

    // G groups of 4 slice-blocks, adapted to available scratch (deterministic).
    int G = 1;
    if (ws_size > (size_t)PART_OFF + 4 * SLICE_ELEMS * sizeof(float)) {
        size_t avail = ws_size - PART_OFF;
        size_t g = avail / (4 * SLICE_ELEMS * sizeof(float));
        G = (int)(g > 128 ? 128 : g);
        if (G < 1) G = 1;
    }

    (void)hipMemsetAsync(counts, 0, KPROTO * sizeof(int), stream);
    proto_prep<<<KPROTO, 256, 0, stream>>>(P, Ph);
    assign_k<<<512, 256, 0, stream>>>(F, Ph, asg, counts);
    segsum_k<<<4 * G, 256, 0, stream>>>(F, asg, partials, G);
    reduce_ema<<<32, 256, 0, stream>>>(partials, counts, P, out, G);
}